// Round 8
// baseline (487.057 us; speedup 1.0000x reference)
//
#include <hip/hip_runtime.h>
#include <math.h>

#define BB 8
#define NN 2048
#define HID 768
#define NHEADS 4
#define VOCAB 15
#define ALPHA 0.2f
#define NEGV -9e15f
#define MTOT (BB * NN)  // 16384

using short4v = __attribute__((ext_vector_type(4))) short;
using short8v = __attribute__((ext_vector_type(8))) short;
using f32x4 = __attribute__((ext_vector_type(4))) float;

__device__ __forceinline__ short f2bf(float f) {
  union { float f; unsigned u; } x;
  x.f = f;
  unsigned r = x.u + 0x7fffu + ((x.u >> 16) & 1u);
  return (short)(r >> 16);
}

__device__ __forceinline__ void cp16(const void* g, void* l) {
  __builtin_amdgcn_global_load_lds(
      (const __attribute__((address_space(1))) unsigned int*)g,
      (__attribute__((address_space(3))) unsigned int*)l, 16, 0, 0);
}

#define MEMFENCE asm volatile("" ::: "memory")
#define SBAR()                         \
  do {                                 \
    MEMFENCE;                          \
    __builtin_amdgcn_s_barrier();      \
    MEMFENCE;                          \
  } while (0)

// ---------------------------------------------------------------------------
// Mega-setup: adjacency bit-pack (4096 vals/block); zero accumulators;
// per-batch vocab bitmasks; W_out transpose; TW partials.
// ---------------------------------------------------------------------------
#define PACK_B 8192
#define ZERO_B 308
#define NFM_B 64
#define TRAN_B 2304  // 96 x 24 tiles of 32x32
#define TW_B 192     // 12 col-chunks x 16 k-chunks
__global__ __launch_bounds__(256) void setup_kernel(
    const int* __restrict__ adj, unsigned long long* __restrict__ packed,
    float* __restrict__ zbase, const int* __restrict__ nf,
    unsigned long long* __restrict__ nfm, const float* __restrict__ W_out,
    short* __restrict__ Wt_o, const float* __restrict__ table,
    const float* __restrict__ W_heads, float* __restrict__ TWp) {
  const int bid = blockIdx.x;
  const int tid = threadIdx.x;
  if (bid < PACK_B) {
    __shared__ unsigned short us[256];
    long base = (long)bid * 4096;
    const int4* ap = (const int4*)(adj + base + tid * 16);
    unsigned nib16 = 0;
#pragma unroll
    for (int k = 0; k < 4; ++k) {
      int4 a = ap[k];
      unsigned nib = (a.x > 0 ? 1u : 0u) | (a.y > 0 ? 2u : 0u) |
                     (a.z > 0 ? 4u : 0u) | (a.w > 0 ? 8u : 0u);
      nib16 |= nib << (4 * k);
    }
    us[tid] = (unsigned short)nib16;
    __syncthreads();
    if (tid < 64) {
      unsigned long long w =
          (unsigned long long)us[4 * tid] |
          ((unsigned long long)us[4 * tid + 1] << 16) |
          ((unsigned long long)us[4 * tid + 2] << 32) |
          ((unsigned long long)us[4 * tid + 3] << 48);
      packed[(base >> 6) + tid] = w;
    }
  } else if (bid < PACK_B + ZERO_B) {
    zbase[(bid - PACK_B) * 256 + tid] = 0.f;
  } else if (bid < PACK_B + ZERO_B + NFM_B) {
    int r = bid - PACK_B - ZERO_B;  // 0..63
    int b = r >> 3, c = r & 7;
    int w = tid >> 6;
    int j = c * 256 + tid;
    int nfv = nf[b * NN + j];
#pragma unroll
    for (int v = 0; v < VOCAB; ++v) {
      unsigned long long m = __ballot(nfv == v);
      if ((tid & 63) == 0) nfm[((long)b * VOCAB + v) * 32 + c * 4 + w] = m;
    }
  } else if (bid < PACK_B + ZERO_B + NFM_B + TRAN_B) {
    // W_out transpose (3072x768 -> bf16 768x3072)
    __shared__ float t[32][33];
    int r2 = bid - PACK_B - ZERO_B - NFM_B;
    const int K = NHEADS * HID, N = HID;
    int k0 = (r2 % 96) * 32, n0 = (r2 / 96) * 32;
    int tx = tid & 31, ty = tid >> 5;
#pragma unroll
    for (int i = 0; i < 32; i += 8)
      t[ty + i][tx] = W_out[(long)(k0 + ty + i) * N + n0 + tx];
    __syncthreads();
#pragma unroll
    for (int i = 0; i < 32; i += 8)
      Wt_o[(long)(n0 + ty + i) * K + k0 + tx] = f2bf(t[tx][ty + i]);
  } else {
    // TW partial: col-chunk cx (256 cols), k-chunk ky (48 k) -> disjoint slot
    __shared__ float tbl[VOCAB][48];
    int r3 = bid - PACK_B - ZERO_B - NFM_B - TRAN_B;  // 0..191
    const int cx = r3 % 12, ky = r3 / 12;
    const int c = cx * 256 + tid;
    const int h = (cx * 256) / HID;
    const int n = c - h * HID;
    const int k0 = ky * 48;
    for (int idx = tid; idx < VOCAB * 48; idx += 256)
      tbl[idx / 48][idx % 48] = table[(idx / 48) * HID + k0 + idx % 48];
    __syncthreads();
    float acc[VOCAB];
#pragma unroll
    for (int v = 0; v < VOCAB; ++v) acc[v] = 0.f;
    const float* wp = W_heads + (long)h * HID * HID + (long)k0 * HID + n;
#pragma unroll 8
    for (int kk = 0; kk < 48; ++kk) {
      float w = wp[(long)kk * HID];
#pragma unroll
      for (int v = 0; v < VOCAB; ++v) acc[v] = fmaf(tbl[v][kk], w, acc[v]);
    }
#pragma unroll
    for (int v = 0; v < VOCAB; ++v)
      TWp[((long)ky * VOCAB + v) * (NHEADS * HID) + c] = acc[v];
  }
}

// ---------------------------------------------------------------------------
// Fused: reduce 16 TW partials -> TW + a-dot partials into TW1/TW2. grid 12.
// ---------------------------------------------------------------------------
__global__ __launch_bounds__(256) void tw_finish_kernel(
    const float* __restrict__ TWp, float* __restrict__ TW,
    const float* __restrict__ a_heads, float* __restrict__ TW1,
    float* __restrict__ TW2) {
  const int tid = threadIdx.x;
  const int c = blockIdx.x * 256 + tid;  // 0..3071
  const int h = (blockIdx.x * 256) / HID;  // uniform per block
  const int n = c - h * HID;
  const float a1 = a_heads[h * 2 * HID + n];
  const float a2 = a_heads[h * 2 * HID + HID + n];
  const int lane = tid & 63;
  const int wv = tid >> 6;
  __shared__ float red[4][2 * VOCAB];

  float s1[VOCAB], s2[VOCAB];
#pragma unroll
  for (int v = 0; v < VOCAB; ++v) {
    float s = 0.f;
#pragma unroll
    for (int ky = 0; ky < 16; ++ky)
      s += TWp[((long)ky * VOCAB + v) * (NHEADS * HID) + c];
    TW[v * (NHEADS * HID) + c] = s;
    s1[v] = s * a1;
    s2[v] = s * a2;
  }
#pragma unroll
  for (int off = 1; off < 64; off <<= 1)
#pragma unroll
    for (int v = 0; v < VOCAB; ++v) {
      s1[v] += __shfl_xor(s1[v], off);
      s2[v] += __shfl_xor(s2[v], off);
    }
  if (lane == 0) {
#pragma unroll
    for (int v = 0; v < VOCAB; ++v) {
      red[wv][v] = s1[v];
      red[wv][VOCAB + v] = s2[v];
    }
  }
  __syncthreads();
  if (tid < 2 * VOCAB) {
    float s = red[0][tid] + red[1][tid] + red[2][tid] + red[3][tid];
    float* dst = (tid < VOCAB) ? (TW1 + h * VOCAB + tid)
                               : (TW2 + h * VOCAB + tid - VOCAB);
    atomicAdd(dst, s);
  }
}

// ---------------------------------------------------------------------------
// P16 via popcount: one wave per row; 15-value softmax for all 4 heads.
// ---------------------------------------------------------------------------
__global__ __launch_bounds__(256) void p16_kernel(
    const int* __restrict__ nf, const unsigned* __restrict__ padj32,
    const unsigned* __restrict__ nfm32, const float* __restrict__ TW1,
    const float* __restrict__ TW2, float* __restrict__ P16) {
  const int t = threadIdx.x;
  const int wv = t >> 6;
  const int lane = t & 63;
  const int rowm = blockIdx.x * 4 + wv;
  const int b = rowm >> 11;
  __shared__ float cnts[4][16];

  unsigned a = padj32[(long)rowm * 64 + lane];
  const unsigned* nb = nfm32 + (long)b * VOCAB * 64 + lane;
  int cnt[VOCAB];
#pragma unroll
  for (int v = 0; v < VOCAB; ++v) cnt[v] = __popc(a & nb[v * 64]);
#pragma unroll
  for (int off = 1; off < 64; off <<= 1)
#pragma unroll
    for (int v = 0; v < VOCAB; ++v) cnt[v] += __shfl_xor(cnt[v], off);
  int cntsum = 0;
#pragma unroll
  for (int v = 0; v < VOCAB; ++v) cntsum += cnt[v];
  const bool use_full = (cntsum == 0);  // wave-uniform
  if (use_full) {
#pragma unroll
    for (int v = 0; v < VOCAB; ++v) cnt[v] = __popc(nb[v * 64]);
#pragma unroll
    for (int off = 1; off < 64; off <<= 1)
#pragma unroll
      for (int v = 0; v < VOCAB; ++v) cnt[v] += __shfl_xor(cnt[v], off);
  }
  if (lane < 16) cnts[wv][lane] = (lane < VOCAB) ? (float)cnt[lane] : 0.f;
  __syncthreads();

  const int h = lane >> 4;
  const int v = lane & 15;
  const int nfi = nf[b * NN + (rowm & 2047)];
  float cvf = cnts[wv][v];
  bool valid = (v < VOCAB) && (cvf > 0.f);
  float logit = 0.f;
  if (!use_full) {
    float s = TW1[h * VOCAB + nfi] + ((v < VOCAB) ? TW2[h * VOCAB + v] : 0.f);
    logit = s > 0.f ? s : ALPHA * s;
  }
  float mv = valid ? logit : -INFINITY;
#pragma unroll
  for (int off = 1; off < 16; off <<= 1) mv = fmaxf(mv, __shfl_xor(mv, off));
  float pv = valid ? cvf * __expf(logit - mv) : 0.f;
  float sum = pv;
#pragma unroll
  for (int off = 1; off < 16; off <<= 1) sum += __shfl_xor(sum, off);
  if (v < VOCAB) P16[((long)h * 16384 + rowm) * 16 + v] = pv / sum;
}

// ---------------------------------------------------------------------------
// hcat[r][h*HID+colh] = ELU( sum_v P16[h][r][v] * TW[v][h*HID+colh] ) -> bf16
// TW slice in registers; P rows as broadcast float4.
// ---------------------------------------------------------------------------
__global__ __launch_bounds__(256) void hcat_expand(
    const float* __restrict__ TW, const float* __restrict__ P16,
    short* __restrict__ hcat) {
  __shared__ float pl[128 * 16];
  const int c0 = blockIdx.x * 128;
  const int r0 = blockIdx.y * 128;
  const int h = c0 / HID;
  const int t = threadIdx.x;
  for (int idx = t; idx < 128 * 16; idx += 256)
    pl[idx] = P16[((long)h * 16384 + r0 + (idx >> 4)) * 16 + (idx & 15)];
  const int clb = (t & 31) * 4;
  const int rlb = (t >> 5) * 16;
  float twc[VOCAB][4];
#pragma unroll
  for (int vv = 0; vv < VOCAB; ++vv) {
    float4 q = *(const float4*)(TW + (long)vv * (NHEADS * HID) + c0 + clb);
    twc[vv][0] = q.x; twc[vv][1] = q.y; twc[vv][2] = q.z; twc[vv][3] = q.w;
  }
  __syncthreads();
#pragma unroll 4
  for (int rr = 0; rr < 16; ++rr) {
    int rl = rlb + rr;
    const float* pr = pl + rl * 16;
    float4 p0 = *(const float4*)(pr);
    float4 p1 = *(const float4*)(pr + 4);
    float4 p2 = *(const float4*)(pr + 8);
    float4 p3 = *(const float4*)(pr + 12);
    float pv[VOCAB] = {p0.x, p0.y, p0.z, p0.w, p1.x, p1.y, p1.z, p1.w,
                       p2.x, p2.y, p2.z, p2.w, p3.x, p3.y, p3.z};
    short4v o;
#pragma unroll
    for (int cc = 0; cc < 4; ++cc) {
      float s = 0.f;
#pragma unroll
      for (int vv = 0; vv < VOCAB; ++vv) s = fmaf(pv[vv], twc[vv][cc], s);
      s = s > 0.f ? s : (__expf(s) - 1.f);
      o[cc] = f2bf(s);
    }
    *(short4v*)(hcat + (long)(r0 + rl) * (NHEADS * HID) + c0 + clb) = o;
  }
}

// ---------------------------------------------------------------------------
// bf16 MFMA GEMM core: 128x384 tile, BK=64, 512 threads (8 waves, each owns
// a 128x48 N-slice). Grid exactly 256 blocks. A,B double-buffered (128 KiB).
// INTRA-WAVE OPERAND PIPELINE: ds_reads for the NEXT MFMA cluster issue
// BEFORE the current cluster (which consumes registers loaded a phase ago),
// waited with counted lgkmcnt. LDS pipe services reads concurrently with
// MFMA within each wave's program order. 2 barriers/tile (both in f1).
//   f0: stage(t+1)[8 vm]; issue a-hi reads[8 ds]; lgkmcnt(8); 24 MFMA(alo×b)
//   f1: vmcnt(0); SBAR; issue alo(t+1)+b(t+1)[14 ds]; lgkmcnt(14);
//       24 MFMA(ahi×b); SBAR
//   Hazards: buf[pn] reads at t.f1 after vmcnt(0)+SBAR (all waves' staging
//   drained); buf writes at (t+1).f0 after t.f1's lgkmcnt+end-SBAR (all
//   waves' reads of that buf complete). b ping-pong via 2-tile unroll
//   (static reg indexing). Compiler's dependency waits guarantee
//   correctness; asm waits pin scheduling.
// MODE 0: a-dot atomics + transposed bf16 Ct. MODE 3: ELU + mean-pool.
// ---------------------------------------------------------------------------
template <int MODE>
__device__ __forceinline__ void gemm_core(
    short (*As)[8192], short (*Bs)[24576],
    const short* __restrict__ A, const short* __restrict__ B,
    int K, int lda, int ldb, int m0, int n0, int z,
    float* __restrict__ Cf, short* __restrict__ Ct,
    const float* __restrict__ a_vec, float* __restrict__ Wh1g,
    float* __restrict__ Wh2g) {
  const int tid = threadIdx.x;
  const int lane = tid & 63;
  const int wid = tid >> 6;  // 0..7: N-slice of 48 cols
  const int l15 = lane & 15;
  const int quad = lane >> 4;
  const int NT = K >> 6;  // even for both call sites (48, 32)
  const int cbase = (quad ^ (l15 & 7)) << 3;

  auto stageA = [&](int kt) {  // 2 cp16/thread
    const short* src = A + (long)m0 * lda + kt * 64;
    short* dst = As[kt & 1];
#pragma unroll
    for (int it = 0; it < 2; ++it) {
      int lin = it * 512 + tid;
      int r = lin >> 3, s = lin & 7;
      cp16(src + (long)r * lda + ((s ^ (r & 7)) << 3), dst + lin * 8);
    }
  };
  auto stageB = [&](int kt) {  // 6 cp16/thread
    const short* src = B + (long)n0 * ldb + kt * 64;
    short* dst = Bs[kt & 1];
#pragma unroll
    for (int it = 0; it < 6; ++it) {
      int lin = it * 512 + tid;
      int r = lin >> 3, s = lin & 7;
      cp16(src + (long)r * ldb + ((s ^ (r & 7)) << 3), dst + lin * 8);
    }
  };

  short8v alo[4][2], ahi[4][2], bA[3][2], bB[3][2];
  f32x4 acc[8][3];
#pragma unroll
  for (int i = 0; i < 8; ++i)
#pragma unroll
    for (int j = 0; j < 3; ++j) acc[i][j] = (f32x4){0.f, 0.f, 0.f, 0.f};

  auto readALO = [&](const short* Ab) {
#pragma unroll
    for (int ii = 0; ii < 4; ++ii) {
      int ro = (ii * 16 + l15) * 64;
      alo[ii][0] = *(const short8v*)(Ab + ro + cbase);
      alo[ii][1] = *(const short8v*)(Ab + ro + (cbase ^ 32));
    }
  };
  auto readAHI = [&](const short* Ab) {
#pragma unroll
    for (int ii = 0; ii < 4; ++ii) {
      int ro = (64 + ii * 16 + l15) * 64;
      ahi[ii][0] = *(const short8v*)(Ab + ro + cbase);
      ahi[ii][1] = *(const short8v*)(Ab + ro + (cbase ^ 32));
    }
  };
  auto readB = [&](const short* Bb, short8v (&bb)[3][2]) {
#pragma unroll
    for (int nj = 0; nj < 3; ++nj) {
      int ro = (wid * 48 + nj * 16 + l15) * 64;
      bb[nj][0] = *(const short8v*)(Bb + ro + cbase);
      bb[nj][1] = *(const short8v*)(Bb + ro + (cbase ^ 32));
    }
  };
  auto mfmaLO = [&](short8v (&bb)[3][2]) {
#pragma unroll
    for (int ii = 0; ii < 4; ++ii)
#pragma unroll
      for (int nj = 0; nj < 3; ++nj) {
        acc[ii][nj] = __builtin_amdgcn_mfma_f32_16x16x32_bf16(
            alo[ii][0], bb[nj][0], acc[ii][nj], 0, 0, 0);
        acc[ii][nj] = __builtin_amdgcn_mfma_f32_16x16x32_bf16(
            alo[ii][1], bb[nj][1], acc[ii][nj], 0, 0, 0);
      }
  };
  auto mfmaHI = [&](short8v (&bb)[3][2]) {
#pragma unroll
    for (int ii = 0; ii < 4; ++ii)
#pragma unroll
      for (int nj = 0; nj < 3; ++nj) {
        acc[4 + ii][nj] = __builtin_amdgcn_mfma_f32_16x16x32_bf16(
            ahi[ii][0], bb[nj][0], acc[4 + ii][nj], 0, 0, 0);
        acc[4 + ii][nj] = __builtin_amdgcn_mfma_f32_16x16x32_bf16(
            ahi[ii][1], bb[nj][1], acc[4 + ii][nj], 0, 0, 0);
      }
  };

  auto tileStep = [&](int t, short8v (&bcur)[3][2], short8v (&bnxt)[3][2]) {
    const int p = t & 1;
    // ---- f0: stage(t+1); issue a-hi reads; counted wait; MFMA lo ----
    if (t + 1 < NT) { stageB(t + 1); stageA(t + 1); }
    readAHI(As[p]);
    asm volatile("s_waitcnt lgkmcnt(8)" ::: "memory");
    __builtin_amdgcn_sched_barrier(0);
    __builtin_amdgcn_s_setprio(1);
    mfmaLO(bcur);
    __builtin_amdgcn_sched_barrier(0);
    __builtin_amdgcn_s_setprio(0);
    // ---- f1: drain staging; issue next-tile operand reads; MFMA hi ----
    if (t + 1 < NT) {
      asm volatile("s_waitcnt vmcnt(0)" ::: "memory");
      SBAR();
      readALO(As[(t + 1) & 1]);
      readB(Bs[(t + 1) & 1], bnxt);
      asm volatile("s_waitcnt lgkmcnt(14)" ::: "memory");
    } else {
      asm volatile("s_waitcnt lgkmcnt(0)" ::: "memory");
      SBAR();
    }
    __builtin_amdgcn_sched_barrier(0);
    __builtin_amdgcn_s_setprio(1);
    mfmaHI(bcur);
    __builtin_amdgcn_sched_barrier(0);
    __builtin_amdgcn_s_setprio(0);
    SBAR();
  };

  // prologue: tile0 staged, drained, operands pre-loaded
  stageA(0);
  stageB(0);
  asm volatile("s_waitcnt vmcnt(0)" ::: "memory");
  SBAR();
  readALO(As[0]);
  readB(Bs[0], bA);

#pragma unroll 1
  for (int t = 0; t < NT; t += 2) {
    tileStep(t, bA, bB);
    tileStep(t + 1, bB, bA);
  }

  // ---- epilogues (C/D: col=l15, row=quad*4+reg per 16x16 frag;
  //      acc[mi][nj]: rows m0+mi*16, cols n0 + wid*48 + nj*16) ----
  if constexpr (MODE == 3) {
#pragma unroll
    for (int nj = 0; nj < 3; ++nj) {
      int col = n0 + wid * 48 + nj * 16 + l15;
      float s = 0.f;
#pragma unroll
      for (int mi = 0; mi < 8; ++mi)
#pragma unroll
        for (int reg = 0; reg < 4; ++reg) {
          float v = acc[mi][nj][reg];
          s += v > 0.f ? v : (__expf(v) - 1.f);
        }
      s += __shfl_xor(s, 16);
      s += __shfl_xor(s, 32);
      if (quad == 0) atomicAdd(Cf + (long)z * HID + col, s * (1.0f / NN));
    }
  } else {  // MODE 0: a-dot atomics + direct transposed Ct store
    float a1v[3], a2v[3];
#pragma unroll
    for (int nj = 0; nj < 3; ++nj) {
      int colh = n0 + wid * 48 + nj * 16 + l15;  // < 768
      a1v[nj] = a_vec[colh];
      a2v[nj] = a_vec[HID + colh];
    }
#pragma unroll
    for (int mi = 0; mi < 8; ++mi) {
      int rb = m0 + mi * 16 + quad * 4;
#pragma unroll
      for (int reg = 0; reg < 4; ++reg) {
        float s1 = 0.f, s2 = 0.f;
#pragma unroll
        for (int nj = 0; nj < 3; ++nj) {
          s1 = fmaf(acc[mi][nj][reg], a1v[nj], s1);
          s2 = fmaf(acc[mi][nj][reg], a2v[nj], s2);
        }
#pragma unroll
        for (int off = 1; off < 16; off <<= 1) {
          s1 += __shfl_xor(s1, off);
          s2 += __shfl_xor(s2, off);
        }
        if (l15 == 0) {
          atomicAdd(Wh1g + rb + reg, s1);
          atomicAdd(Wh2g + rb + reg, s2);
        }
      }
    }
    const int bb = m0 >> 11;
    const int ml0 = m0 & 2047;
#pragma unroll
    for (int mi = 0; mi < 8; ++mi) {
#pragma unroll
      for (int nj = 0; nj < 3; ++nj) {
        int colh = n0 + wid * 48 + nj * 16 + l15;
        short4v pk;
#pragma unroll
        for (int reg = 0; reg < 4; ++reg) pk[reg] = f2bf(acc[mi][nj][reg]);
        *(short4v*)(Ct + ((long)bb * HID + colh) * NN + ml0 + mi * 16 +
                    quad * 4) = pk;
      }
    }
  }
}

// Layer-2 projection: hcat(16384x3072) x Wt_o(768x3072)^T. Grid 256.
__global__ __launch_bounds__(512, 2) void gemm_proj(
    const short* __restrict__ Ahc, const short* __restrict__ Bw,
    short* __restrict__ Ct, const float* __restrict__ a_vec,
    float* __restrict__ Wh1g, float* __restrict__ Wh2g) {
  __shared__ short As[2][8192];
  __shared__ short Bs[2][24576];
  int bid = blockIdx.x;
  int work = (bid & 7) * 32 + (bid >> 3);  // XCD-contiguous
  int bx = work >> 7;        // 0..1  (bx-major: 4 XCDs per B panel)
  int by = work & 127;       // 0..127
  gemm_core<0>(As, Bs, Ahc, Bw, NHEADS * HID, NHEADS * HID, NHEADS * HID,
               by * 128, bx * 384, 0, nullptr, Ct, a_vec, Wh1g, Wh2g);
}

// Attention aggregate: att2[z](2048x2048) x Wh_t[z](768x2048)^T. Grid 256.
__global__ __launch_bounds__(512, 2) void gemm_attn(
    const short* __restrict__ att, const short* __restrict__ WhT,
    float* __restrict__ Cf) {
  __shared__ short As[2][8192];
  __shared__ short Bs[2][24576];
  int bid = blockIdx.x;
  int work = (bid & 7) * 32 + (bid >> 3);
  int z = work >> 5;         // one batch per XCD
  int rem = work & 31;
  int bx = rem >> 4;         // 0..1
  int by = rem & 15;         // 0..15
  gemm_core<3>(As, Bs, att + (long)z * NN * NN, WhT + (long)z * HID * NN,
               NN, NN, NN, by * 128, bx * 384, z, Cf, nullptr, nullptr,
               nullptr, nullptr);
}

// ---------------------------------------------------------------------------
// Layer-2 row softmax (materializing, bf16 att). 8 rows/block, Wh2 row in
// registers. grid 2048. Blocks [0,zn) also zero zA.
// ---------------------------------------------------------------------------
__global__ __launch_bounds__(256) void attn_softmax_kernel(
    const float* __restrict__ Wh1, const float* __restrict__ Wh2,
    const unsigned long long* __restrict__ packed, short* __restrict__ att,
    float* __restrict__ zA, int zn) {
  const int bid = blockIdx.x;
  const int t = threadIdx.x;
  if (bid < zn) zA[bid * 256 + t] = 0.f;
  const int b = bid >> 8;
  const int row0 = bid * 8;
  const int lane = t & 63;
  const int wv = t >> 6;
  const float* wh2b = Wh2 + b * NN;

  float4 wa = ((const float4*)(wh2b + t * 8))[0];
  float4 wb = ((const float4*)(wh2b + t * 8))[1];
  float w[8] = {wa.x, wa.y, wa.z, wa.w, wb.x, wb.y, wb.z, wb.w};

  __shared__ float redm[4], reds[4];
#pragma unroll 1
  for (int r = 0; r < 8; ++r) {
    const int row = row0 + r;
    unsigned m8 = ((const unsigned char*)(packed + (long)row * 32))[t];
    float wh1 = Wh1[row];
    float v[8];
    float lmax = -INFINITY;
#pragma unroll
    for (int k = 0; k < 8; ++k) {
      float s = wh1 + w[k];
      s = s > 0.f ? s : ALPHA * s;
      s = ((m8 >> k) & 1u) ? s : NEGV;
      v[k] = s;
      lmax = fmaxf(lmax, s);
    }
#pragma unroll
    for (int off = 32; off > 0; off >>= 1)
      lmax = fmaxf(lmax, __shfl_xor(lmax, off));
    if (lane == 0) redm[wv] = lmax;
    __syncthreads();
    float m = fmaxf(fmaxf(redm[0], redm[1]), fmaxf(redm[2], redm[3]));

    float lsum = 0.f;
#pragma unroll
    for (int k = 0; k < 8; ++k) {
      float p = __expf(v[k] - m);
      v[k] = p;
      lsum += p;
    }
#pragma unroll
    for (int off = 32; off > 0; off >>= 1) lsum += __shfl_xor(lsum, off);
    if (lane == 0) reds[wv] = lsum;
    __syncthreads();
    float inv = 1.f / (reds[0] + reds[1] + reds[2] + reds[3]);

    short8v o;
#pragma unroll
    for (int k = 0; k < 8; ++k) o[k] = f2bf(v[k] * inv);
    *(short8v*)(att + (long)row * NN + t * 8) = o;
  }
}

// ---------------------------------------------------------------------------
extern "C" void kernel_launch(void* const* d_in, const int* in_sizes, int n_in,
                              void* d_out, int out_size, void* d_ws,
                              size_t ws_size, hipStream_t stream) {
  const int* node_feats = (const int*)d_in[0];
  const int* adjs = (const int*)d_in[1];
  const float* embed_table = (const float*)d_in[2];
  const float* W_heads = (const float*)d_in[3];
  const float* a_heads = (const float*)d_in[4];
  const float* W_out = (const float*)d_in[5];
  const float* a_out = (const float*)d_in[6];
  float* out = (float*)d_out;

  // workspace layout (~215 MB)
  char* p = (char*)d_ws;
  short* Wt_o = (short*)p;  p += (size_t)HID * (NHEADS * HID) * 2;       // 4.7 MB
  short* Wh_t = (short*)p;  p += (size_t)BB * HID * NN * 2;              // 25 MB
  short* att2 = (short*)p;  p += (size_t)BB * NN * NN * 2;               // 67 MB
  short* hcat = (short*)p;  p += (size_t)MTOT * NHEADS * HID * 2;        // 100 MB
  unsigned long long* padj = (unsigned long long*)p;
  p += (size_t)BB * NN * NN / 8;                                         // 4.2 MB
  float* P16 = (float*)p;   p += (size_t)NHEADS * 16384 * 16 * 4;        // 4 MB
  // zero region (ZERO_B*256 floats): Wh1, Wh2, TW1, TW2, pad
  float* Wh1 = (float*)p;   p += (size_t)16384 * 4;
  float* Wh2 = (float*)p;   p += (size_t)16384 * 4;
  float* TW1 = (float*)p;   p += (size_t)64 * 4;
  float* TW2 = (float*)p;   p += (size_t)64 * 4;
  p += (size_t)(ZERO_B * 256 - 2 * 16384 - 128) * 4;  // pad (zeroed)
  float* TWp = (float*)p;   p += (size_t)16 * VOCAB * NHEADS * HID * 4;  // 2.9 MB
  float* TW = (float*)p;    p += (size_t)VOCAB * NHEADS * HID * 4;
  unsigned long long* nfm = (unsigned long long*)p;
  p += (size_t)BB * VOCAB * 32 * 8;                                      // 30 KB
  if ((size_t)(p - (char*)d_ws) > ws_size) return;

  // 0) mega-setup: adj pack + zeros + vocab masks + transpose + TW
  setup_kernel<<<PACK_B + ZERO_B + NFM_B + TRAN_B + TW_B, 256, 0, stream>>>(
      adjs, padj, Wh1, node_feats, nfm, W_out, Wt_o, embed_table, W_heads,
      TWp);

  // 1) layer 1: TW reduce + a-dots (fused), popcount-P16, expand
  tw_finish_kernel<<<12, 256, 0, stream>>>(TWp, TW, a_heads, TW1, TW2);
  p16_kernel<<<16384 / 4, 256, 0, stream>>>(
      node_feats, (const unsigned*)padj, (const unsigned*)nfm, TW1, TW2, P16);
  hcat_expand<<<dim3(24, 128), 256, 0, stream>>>(TW, P16, hcat);

  // 2) output GAT layer: proj -> Wh_t + Wh1/Wh2 atomics; softmax; aggregate
  gemm_proj<<<256, 512, 0, stream>>>(hcat, Wt_o, Wh_t, a_out, Wh1, Wh2);
  attn_softmax_kernel<<<MTOT / 8, 256, 0, stream>>>(Wh1, Wh2, padj, att2, out,
                                                    24);
  gemm_attn<<<256, 512, 0, stream>>>(att2, Wh_t, out);
}

// Round 10
// 443.354 us; speedup vs baseline: 1.0986x; 1.0986x over previous
//
#include <hip/hip_runtime.h>
#include <math.h>

#define BB 8
#define NN 2048
#define HID 768
#define NHEADS 4
#define VOCAB 15
#define ALPHA 0.2f
#define NEGV -9e15f
#define MTOT (BB * NN)  // 16384

using short4v = __attribute__((ext_vector_type(4))) short;
using short8v = __attribute__((ext_vector_type(8))) short;
using f32x4 = __attribute__((ext_vector_type(4))) float;

__device__ __forceinline__ short f2bf(float f) {
  union { float f; unsigned u; } x;
  x.f = f;
  unsigned r = x.u + 0x7fffu + ((x.u >> 16) & 1u);
  return (short)(r >> 16);
}

__device__ __forceinline__ void cp16(const void* g, void* l) {
  __builtin_amdgcn_global_load_lds(
      (const __attribute__((address_space(1))) unsigned int*)g,
      (__attribute__((address_space(3))) unsigned int*)l, 16, 0, 0);
}

// pack 8 bytes' low nibbles (LE order) into 32 bits
__device__ __forceinline__ unsigned long long nibcompress(unsigned long long x) {
  x = (x | (x >> 4)) & 0x00FF00FF00FF00FFull;
  x = (x | (x >> 8)) & 0x0000FFFF0000FFFFull;
  x = (x | (x >> 16)) & 0x00000000FFFFFFFFull;
  return x;
}

#define MEMFENCE asm volatile("" ::: "memory")
#define SBAR()                         \
  do {                                 \
    MEMFENCE;                          \
    __builtin_amdgcn_s_barrier();      \
    MEMFENCE;                          \
  } while (0)

// ---------------------------------------------------------------------------
// Mega-setup: [0,PACK_B) adjacency bit-pack, int4-vectorized (1024/block);
// [+ZERO_B) zero {Wh1,Wh2,TW1,TW2,pad}; [+NFM_B) per-batch vocab bitmasks;
// [+TRAN_B) W_out transpose; [+TW_B) TW partials (per-ky disjoint slots).
// ---------------------------------------------------------------------------
#define PACK_B 32768
#define ZERO_B 308
#define NFM_B 64
#define TRAN_B 2304  // 96 x 24 tiles of 32x32
#define TW_B 192     // 12 col-chunks x 16 k-chunks
__global__ __launch_bounds__(256) void setup_kernel(
    const int* __restrict__ adj, unsigned long long* __restrict__ packed,
    float* __restrict__ zbase, const int* __restrict__ nf,
    unsigned long long* __restrict__ nfm, const float* __restrict__ W_out,
    short* __restrict__ Wt_o, const float* __restrict__ table,
    const float* __restrict__ W_heads, float* __restrict__ TWp) {
  const int bid = blockIdx.x;
  const int tid = threadIdx.x;
  if (bid < PACK_B) {
    __shared__ unsigned long long nibq[32];
    long base = (long)bid * 1024;
    int4 a = *(const int4*)(adj + base + tid * 4);
    unsigned nib = (a.x > 0 ? 1u : 0u) | (a.y > 0 ? 2u : 0u) |
                   (a.z > 0 ? 4u : 0u) | (a.w > 0 ? 8u : 0u);
    ((unsigned char*)nibq)[tid] = (unsigned char)nib;
    __syncthreads();
    if (tid < 16) {
      unsigned long long lo = nibcompress(nibq[2 * tid]);
      unsigned long long hi = nibcompress(nibq[2 * tid + 1]);
      packed[(base >> 6) + tid] = lo | (hi << 32);
    }
  } else if (bid < PACK_B + ZERO_B) {
    zbase[(bid - PACK_B) * 256 + tid] = 0.f;
  } else if (bid < PACK_B + ZERO_B + NFM_B) {
    int r = bid - PACK_B - ZERO_B;  // 0..63
    int b = r >> 3, c = r & 7;
    int w = tid >> 6;
    int j = c * 256 + tid;
    int nfv = nf[b * NN + j];
#pragma unroll
    for (int v = 0; v < VOCAB; ++v) {
      unsigned long long m = __ballot(nfv == v);
      if ((tid & 63) == 0) nfm[((long)b * VOCAB + v) * 32 + c * 4 + w] = m;
    }
  } else if (bid < PACK_B + ZERO_B + NFM_B + TRAN_B) {
    // W_out transpose (3072x768 -> bf16 768x3072)
    __shared__ float t[32][33];
    int r2 = bid - PACK_B - ZERO_B - NFM_B;
    const int K = NHEADS * HID, N = HID;
    int k0 = (r2 % 96) * 32, n0 = (r2 / 96) * 32;
    int tx = tid & 31, ty = tid >> 5;
#pragma unroll
    for (int i = 0; i < 32; i += 8)
      t[ty + i][tx] = W_out[(long)(k0 + ty + i) * N + n0 + tx];
    __syncthreads();
#pragma unroll
    for (int i = 0; i < 32; i += 8)
      Wt_o[(long)(n0 + ty + i) * K + k0 + tx] = f2bf(t[tx][ty + i]);
  } else {
    // TW partial: col-chunk cx (256 cols), k-chunk ky (48 k) -> disjoint slot
    __shared__ float tbl[VOCAB][48];
    int r3 = bid - PACK_B - ZERO_B - NFM_B - TRAN_B;  // 0..191
    const int cx = r3 % 12, ky = r3 / 12;
    const int c = cx * 256 + tid;
    const int h = (cx * 256) / HID;
    const int n = c - h * HID;
    const int k0 = ky * 48;
    for (int idx = tid; idx < VOCAB * 48; idx += 256)
      tbl[idx / 48][idx % 48] = table[(idx / 48) * HID + k0 + idx % 48];
    __syncthreads();
    float acc[VOCAB];
#pragma unroll
    for (int v = 0; v < VOCAB; ++v) acc[v] = 0.f;
    const float* wp = W_heads + (long)h * HID * HID + (long)k0 * HID + n;
#pragma unroll 8
    for (int kk = 0; kk < 48; ++kk) {
      float w = wp[(long)kk * HID];
#pragma unroll
      for (int v = 0; v < VOCAB; ++v) acc[v] = fmaf(tbl[v][kk], w, acc[v]);
    }
#pragma unroll
    for (int v = 0; v < VOCAB; ++v)
      TWp[((long)ky * VOCAB + v) * (NHEADS * HID) + c] = acc[v];
  }
}

// ---------------------------------------------------------------------------
// Fused: reduce 16 TW partials -> TW, and accumulate a-dot partials into
// TW1/TW2 (zeroed by setup) via per-block reduce + atomicAdd. grid 12.
// ---------------------------------------------------------------------------
__global__ __launch_bounds__(256) void tw_finish_kernel(
    const float* __restrict__ TWp, float* __restrict__ TW,
    const float* __restrict__ a_heads, float* __restrict__ TW1,
    float* __restrict__ TW2) {
  const int tid = threadIdx.x;
  const int c = blockIdx.x * 256 + tid;  // 0..3071
  const int h = (blockIdx.x * 256) / HID;  // uniform per block
  const int n = c - h * HID;
  const float a1 = a_heads[h * 2 * HID + n];
  const float a2 = a_heads[h * 2 * HID + HID + n];
  const int lane = tid & 63;
  const int wv = tid >> 6;
  __shared__ float red[4][2 * VOCAB];

  float s1[VOCAB], s2[VOCAB];
#pragma unroll
  for (int v = 0; v < VOCAB; ++v) {
    float s = 0.f;
#pragma unroll
    for (int ky = 0; ky < 16; ++ky)
      s += TWp[((long)ky * VOCAB + v) * (NHEADS * HID) + c];
    TW[v * (NHEADS * HID) + c] = s;
    s1[v] = s * a1;
    s2[v] = s * a2;
  }
#pragma unroll
  for (int off = 1; off < 64; off <<= 1)
#pragma unroll
    for (int v = 0; v < VOCAB; ++v) {
      s1[v] += __shfl_xor(s1[v], off);
      s2[v] += __shfl_xor(s2[v], off);
    }
  if (lane == 0) {
#pragma unroll
    for (int v = 0; v < VOCAB; ++v) {
      red[wv][v] = s1[v];
      red[wv][VOCAB + v] = s2[v];
    }
  }
  __syncthreads();
  if (tid < 2 * VOCAB) {
    float s = red[0][tid] + red[1][tid] + red[2][tid] + red[3][tid];
    float* dst = (tid < VOCAB) ? (TW1 + h * VOCAB + tid)
                               : (TW2 + h * VOCAB + tid - VOCAB);
    atomicAdd(dst, s);
  }
}

// ---------------------------------------------------------------------------
// P16 via popcount: one wave per row; 15-value softmax for all 4 heads.
// ---------------------------------------------------------------------------
__global__ __launch_bounds__(256) void p16_kernel(
    const int* __restrict__ nf, const unsigned* __restrict__ padj32,
    const unsigned* __restrict__ nfm32, const float* __restrict__ TW1,
    const float* __restrict__ TW2, float* __restrict__ P16) {
  const int t = threadIdx.x;
  const int wv = t >> 6;
  const int lane = t & 63;
  const int rowm = blockIdx.x * 4 + wv;
  const int b = rowm >> 11;
  __shared__ float cnts[4][16];

  unsigned a = padj32[(long)rowm * 64 + lane];
  const unsigned* nb = nfm32 + (long)b * VOCAB * 64 + lane;
  int cnt[VOCAB];
#pragma unroll
  for (int v = 0; v < VOCAB; ++v) cnt[v] = __popc(a & nb[v * 64]);
#pragma unroll
  for (int off = 1; off < 64; off <<= 1)
#pragma unroll
    for (int v = 0; v < VOCAB; ++v) cnt[v] += __shfl_xor(cnt[v], off);
  int cntsum = 0;
#pragma unroll
  for (int v = 0; v < VOCAB; ++v) cntsum += cnt[v];
  const bool use_full = (cntsum == 0);  // wave-uniform
  if (use_full) {
#pragma unroll
    for (int v = 0; v < VOCAB; ++v) cnt[v] = __popc(nb[v * 64]);
#pragma unroll
    for (int off = 1; off < 64; off <<= 1)
#pragma unroll
      for (int v = 0; v < VOCAB; ++v) cnt[v] += __shfl_xor(cnt[v], off);
  }
  if (lane < 16) cnts[wv][lane] = (lane < VOCAB) ? (float)cnt[lane] : 0.f;
  __syncthreads();

  const int h = lane >> 4;
  const int v = lane & 15;
  const int nfi = nf[b * NN + (rowm & 2047)];
  float cvf = cnts[wv][v];
  bool valid = (v < VOCAB) && (cvf > 0.f);
  float logit = 0.f;
  if (!use_full) {
    float s = TW1[h * VOCAB + nfi] + ((v < VOCAB) ? TW2[h * VOCAB + v] : 0.f);
    logit = s > 0.f ? s : ALPHA * s;
  }
  float mv = valid ? logit : -INFINITY;
#pragma unroll
  for (int off = 1; off < 16; off <<= 1) mv = fmaxf(mv, __shfl_xor(mv, off));
  float pv = valid ? cvf * __expf(logit - mv) : 0.f;
  float sum = pv;
#pragma unroll
  for (int off = 1; off < 16; off <<= 1) sum += __shfl_xor(sum, off);
  if (v < VOCAB) P16[((long)h * 16384 + rowm) * 16 + v] = pv / sum;
}

// ---------------------------------------------------------------------------
// hcat[r][h*HID+colh] = ELU( sum_v P16[h][r][v] * TW[v][h*HID+colh] ) -> bf16
// ---------------------------------------------------------------------------
__global__ __launch_bounds__(256) void hcat_expand(
    const float* __restrict__ TW, const float* __restrict__ P16,
    short* __restrict__ hcat) {
  __shared__ float twl[VOCAB * 128];
  __shared__ float pl[128 * 16];
  const int c0 = blockIdx.x * 128;
  const int r0 = blockIdx.y * 128;
  const int h = c0 / HID;
  const int t = threadIdx.x;
  for (int idx = t; idx < VOCAB * 128; idx += 256)
    twl[idx] = TW[(idx / 128) * (NHEADS * HID) + c0 + (idx & 127)];
  for (int idx = t; idx < 128 * 16; idx += 256)
    pl[idx] = P16[((long)h * 16384 + r0 + (idx >> 4)) * 16 + (idx & 15)];
  __syncthreads();
  const int clb = (t & 31) * 4;
  const int rlb = (t >> 5) * 16;
#pragma unroll 4
  for (int rr = 0; rr < 16; ++rr) {
    int rl = rlb + rr;
    short4v o;
#pragma unroll
    for (int cc = 0; cc < 4; ++cc) {
      float s = 0.f;
#pragma unroll
      for (int vv = 0; vv < VOCAB; ++vv)
        s = fmaf(pl[rl * 16 + vv], twl[vv * 128 + clb + cc], s);
      s = s > 0.f ? s : (__expf(s) - 1.f);
      o[cc] = f2bf(s);
    }
    *(short4v*)(hcat + (long)(r0 + rl) * (NHEADS * HID) + c0 + clb) = o;
  }
}

// ---------------------------------------------------------------------------
// bf16 MFMA GEMM, 256x256 tile, BK=64, 512 threads (8 waves, 2Mx4N),
// 4 phases/K-tile (round-1 structure). DEEPENED PIPELINE: both operands
// staged 2 tiles ahead — stage B(t+2) at q2 (B LDS slots free after q1's
// trailing barrier), A(t+2) at q3 (A slots free after q2); steady-state
// vmcnt(8) at q3 (16 outstanding -> drains t+1's 8, keeps t+2's 8 in
// flight ~6 phases). K-chunk XOR swizzle via pre-swizzled global source +
// swizzled ds_read. 128 KiB LDS double-buffer.
//   Ledger: prologue stages tiles 0,1 (16 loads), vmcnt(8) lands tile 0.
//   Tile t q3-end: outstanding 16 -> vmcnt(8); t=NT-2: vmcnt(0) tail.
//   Slot-free: B halves last read q1 (wc quarters), A halves last read q2
//   (wr halves) -> q2/q3 staging into buf[t&1] is write-after-read safe.
// MODE 0: a-dot atomics + transposed bf16 Ct [bb][colh][row] (layer 2).
// MODE 3: fused ELU + mean-pool: atomicAdd Cf[z*HID + col].
// ---------------------------------------------------------------------------
template <int MODE>
__global__ __launch_bounds__(512, 2) void mfma_gemm(
    const short* __restrict__ A, const short* __restrict__ B,
    int K, int lda, int ldb, long sA, long sB,
    float* __restrict__ Cf, short* __restrict__ Ct,
    const float* __restrict__ a_vec, float* __restrict__ Wh1g,
    float* __restrict__ Wh2g) {
  __shared__ short lds[2][2][16384];  // [buf][A/B][256 rows * 64 k] = 128 KiB

  const int gx = gridDim.x, gy = gridDim.y;
  int linb = blockIdx.x + gx * (blockIdx.y + gy * blockIdx.z);
  const int per = (gx * gy * gridDim.z) >> 3;
  int work = (linb & 7) * per + (linb >> 3);
  int bx, by, z;
  if constexpr (MODE == 0) {
    bx = work / gy;  // bx-major: each XCD works within ~1 B panel
    by = work % gy;
    z = 0;
  } else {
    bx = work % gx;
    int tm = work / gx;
    by = tm % gy;
    z = tm / gy;
  }

  A += (long)z * sA;
  B += (long)z * sB;

  const int tid = threadIdx.x;
  const int m0 = by * 256;
  const int n0 = bx * 256;
  const int lane = tid & 63;
  const int wid = tid >> 6;
  const int wr = wid >> 2;  // 0..1  (M half)
  const int wc = wid & 3;   // 0..3  (N quarter)
  const int l15 = lane & 15;
  const int quad = lane >> 4;
  const int NT = K >> 6;  // 48 (proj), 32 (attn) — both >= 3
  const int cbase = (quad ^ (l15 & 7)) << 3;

  auto stageA = [&](int kt, int h) {
    const short* src = A + (long)(m0 + h * 128) * lda + kt * 64;
    short* dst = &lds[kt & 1][0][h * 8192];
#pragma unroll
    for (int it = 0; it < 2; ++it) {
      int r = it * 64 + (tid >> 3);
      int s = tid & 7;
      cp16(src + (long)r * lda + ((s ^ (r & 7)) << 3),
           dst + (it * 512 + tid) * 8);
    }
  };
  auto stageB = [&](int kt, int h) {
    const short* src = B + (long)(n0 + h * 128) * ldb + kt * 64;
    short* dst = &lds[kt & 1][1][h * 8192];
#pragma unroll
    for (int it = 0; it < 2; ++it) {
      int r = it * 64 + (tid >> 3);
      int s = tid & 7;
      cp16(src + (long)r * ldb + ((s ^ (r & 7)) << 3),
           dst + (it * 512 + tid) * 8);
    }
  };

  f32x4 acc[8][4];
#pragma unroll
  for (int i = 0; i < 8; ++i)
#pragma unroll
    for (int j = 0; j < 4; ++j) acc[i][j] = (f32x4){0.f, 0.f, 0.f, 0.f};

  // prologue: tiles 0 and 1 fully staged; vmcnt(8) lands tile 0,
  // keeps tile 1's 8 loads in flight across tile 0's compute.
  stageA(0, 0); stageA(0, 1);
  stageB(0, 0); stageB(0, 1);
  stageA(1, 0); stageA(1, 1);
  stageB(1, 0); stageB(1, 1);
  asm volatile("s_waitcnt vmcnt(8)" ::: "memory");
  SBAR();

#pragma unroll 1
  for (int t = 0; t < NT; ++t) {
    const int p = t & 1;
    const short* Ab = &lds[p][0][0];
    const short* Bb = &lds[p][1][0];
    short8v a[4][2], b0[2][2], b1[2][2];

    // ---- q0: read A(qm=0) + B(qn=0); MFMA Q00 ----
#pragma unroll
    for (int ii = 0; ii < 4; ++ii) {
      int ro = (wr * 128 + ii * 16 + l15) * 64;
      a[ii][0] = *(const short8v*)(Ab + ro + cbase);
      a[ii][1] = *(const short8v*)(Ab + ro + (cbase ^ 32));
    }
#pragma unroll
    for (int jj = 0; jj < 2; ++jj) {
      int ro = (wc * 64 + jj * 16 + l15) * 64;
      b0[jj][0] = *(const short8v*)(Bb + ro + cbase);
      b0[jj][1] = *(const short8v*)(Bb + ro + (cbase ^ 32));
    }
    SBAR();
    asm volatile("s_waitcnt lgkmcnt(0)" ::: "memory");
    __builtin_amdgcn_sched_barrier(0);
    __builtin_amdgcn_s_setprio(1);
#pragma unroll
    for (int ii = 0; ii < 4; ++ii)
#pragma unroll
      for (int jj = 0; jj < 2; ++jj) {
        acc[ii][jj] = __builtin_amdgcn_mfma_f32_16x16x32_bf16(
            a[ii][0], b0[jj][0], acc[ii][jj], 0, 0, 0);
        acc[ii][jj] = __builtin_amdgcn_mfma_f32_16x16x32_bf16(
            a[ii][1], b0[jj][1], acc[ii][jj], 0, 0, 0);
      }
    __builtin_amdgcn_sched_barrier(0);
    __builtin_amdgcn_s_setprio(0);
    SBAR();

    // ---- q1: read B(qn=1); MFMA Q01 ----
#pragma unroll
    for (int jj = 0; jj < 2; ++jj) {
      int ro = (wc * 64 + 32 + jj * 16 + l15) * 64;
      b1[jj][0] = *(const short8v*)(Bb + ro + cbase);
      b1[jj][1] = *(const short8v*)(Bb + ro + (cbase ^ 32));
    }
    SBAR();
    asm volatile("s_waitcnt lgkmcnt(0)" ::: "memory");
    __builtin_amdgcn_sched_barrier(0);
    __builtin_amdgcn_s_setprio(1);
#pragma unroll
    for (int ii = 0; ii < 4; ++ii)
#pragma unroll
      for (int jj = 0; jj < 2; ++jj) {
        acc[ii][2 + jj] = __builtin_amdgcn_mfma_f32_16x16x32_bf16(
            a[ii][0], b1[jj][0], acc[ii][2 + jj], 0, 0, 0);
        acc[ii][2 + jj] = __builtin_amdgcn_mfma_f32_16x16x32_bf16(
            a[ii][1], b1[jj][1], acc[ii][2 + jj], 0, 0, 0);
      }
    __builtin_amdgcn_sched_barrier(0);
    __builtin_amdgcn_s_setprio(0);
    SBAR();

    // ---- q2: issue B(t+2) (B slots of buf p free since q1's trailing
    //          barrier); read A(qm=1); MFMA Q11 ----
    if (t + 2 < NT) { stageB(t + 2, 0); stageB(t + 2, 1); }
#pragma unroll
    for (int ii = 0; ii < 4; ++ii) {
      int ro = (wr * 128 + 64 + ii * 16 + l15) * 64;
      a[ii][0] = *(const short8v*)(Ab + ro + cbase);
      a[ii][1] = *(const short8v*)(Ab + ro + (cbase ^ 32));
    }
    SBAR();
    asm volatile("s_waitcnt lgkmcnt(0)" ::: "memory");
    __builtin_amdgcn_sched_barrier(0);
    __builtin_amdgcn_s_setprio(1);
#pragma unroll
    for (int ii = 0; ii < 4; ++ii)
#pragma unroll
      for (int jj = 0; jj < 2; ++jj) {
        acc[4 + ii][2 + jj] = __builtin_amdgcn_mfma_f32_16x16x32_bf16(
            a[ii][0], b1[jj][0], acc[4 + ii][2 + jj], 0, 0, 0);
        acc[4 + ii][2 + jj] = __builtin_amdgcn_mfma_f32_16x16x32_bf16(
            a[ii][1], b1[jj][1], acc[4 + ii][2 + jj], 0, 0, 0);
      }
    __builtin_amdgcn_sched_barrier(0);
    __builtin_amdgcn_s_setprio(0);
    SBAR();

    // ---- q3: issue A(t+2) (A slots free since q2's trailing barrier);
    //          MFMA Q10; counted vmcnt(8) keeps t+2 in flight ----
    if (t + 2 < NT) { stageA(t + 2, 0); stageA(t + 2, 1); }
    __builtin_amdgcn_s_setprio(1);
#pragma unroll
    for (int ii = 0; ii < 4; ++ii)
#pragma unroll
      for (int jj = 0; jj < 2; ++jj) {
        acc[4 + ii][jj] = __builtin_amdgcn_mfma_f32_16x16x32_bf16(
            a[ii][0], b0[jj][0], acc[4 + ii][jj], 0, 0, 0);
        acc[4 + ii][jj] = __builtin_amdgcn_mfma_f32_16x16x32_bf16(
            a[ii][1], b0[jj][1], acc[4 + ii][jj], 0, 0, 0);
      }
    __builtin_amdgcn_sched_barrier(0);
    __builtin_amdgcn_s_setprio(0);
    if (t + 2 < NT) {
      asm volatile("s_waitcnt vmcnt(8)" ::: "memory");
    } else if (t + 1 < NT) {
      asm volatile("s_waitcnt vmcnt(0)" ::: "memory");
    }
    SBAR();
  }

  // ---- epilogues (C/D layout: col=l15, row=quad*4+reg per 16x16 frag;
  //      acc[mi][nj] covers rows wr*128+mi*16, cols wc*64+nj*16) ----
  if constexpr (MODE == 3) {
#pragma unroll
    for (int nj = 0; nj < 4; ++nj) {
      int col = n0 + wc * 64 + nj * 16 + l15;
      float s = 0.f;
#pragma unroll
      for (int mi = 0; mi < 8; ++mi)
#pragma unroll
        for (int reg = 0; reg < 4; ++reg) {
          float v = acc[mi][nj][reg];
          s += v > 0.f ? v : (__expf(v) - 1.f);
        }
      s += __shfl_xor(s, 16);
      s += __shfl_xor(s, 32);
      if (quad == 0) atomicAdd(Cf + (long)z * HID + col, s * (1.0f / NN));
    }
  } else {  // MODE 0: a-dot atomics + direct transposed Ct store
    float a1v[4], a2v[4];
#pragma unroll
    for (int nj = 0; nj < 4; ++nj) {
      int colh = n0 + wc * 64 + nj * 16 + l15;  // < 768
      a1v[nj] = a_vec[colh];
      a2v[nj] = a_vec[HID + colh];
    }
#pragma unroll
    for (int mi = 0; mi < 8; ++mi) {
      int rb = m0 + wr * 128 + mi * 16 + quad * 4;
#pragma unroll
      for (int reg = 0; reg < 4; ++reg) {
        float s1 = 0.f, s2 = 0.f;
#pragma unroll
        for (int nj = 0; nj < 4; ++nj) {
          s1 = fmaf(acc[mi][nj][reg], a1v[nj], s1);
          s2 = fmaf(acc[mi][nj][reg], a2v[nj], s2);
        }
#pragma unroll
        for (int off = 1; off < 16; off <<= 1) {
          s1 += __shfl_xor(s1, off);
          s2 += __shfl_xor(s2, off);
        }
        if (l15 == 0) {
          atomicAdd(Wh1g + rb + reg, s1);
          atomicAdd(Wh2g + rb + reg, s2);
        }
      }
    }
    const int bb = m0 >> 11;
    const int ml0 = (m0 & 2047) + wr * 128;
#pragma unroll
    for (int mi = 0; mi < 8; ++mi) {
#pragma unroll
      for (int nj = 0; nj < 4; ++nj) {
        int colh = n0 + wc * 64 + nj * 16 + l15;
        short4v pk;
#pragma unroll
        for (int reg = 0; reg < 4; ++reg) pk[reg] = f2bf(acc[mi][nj][reg]);
        *(short4v*)(Ct + ((long)bb * HID + colh) * NN + ml0 + mi * 16 +
                    quad * 4) = pk;
      }
    }
  }
}

// ---------------------------------------------------------------------------
// Layer-2 row softmax (materializing, bf16 att). grid 16384. Blocks [0,zn)
// also zero zA (final output accumulator; write-disjoint from reads).
// ---------------------------------------------------------------------------
__global__ __launch_bounds__(256) void attn_softmax_kernel(
    const float* __restrict__ Wh1, const float* __restrict__ Wh2,
    const unsigned long long* __restrict__ packed, short* __restrict__ att,
    float* __restrict__ zA, int zn) {
  int row = blockIdx.x;
  if (row < zn) zA[row * 256 + threadIdx.x] = 0.f;
  int b = row >> 11;
  const unsigned char* bits = (const unsigned char*)(packed + (long)row * 32);
  const float* wh2b = Wh2 + b * NN;
  const int t = threadIdx.x;
  const int lane = t & 63;
  const int wv = t >> 6;

  unsigned m8 = bits[t];
  float wh1 = Wh1[row];
  float4 wa = ((const float4*)(wh2b + t * 8))[0];
  float4 wb = ((const float4*)(wh2b + t * 8))[1];
  float v[8] = {wa.x, wa.y, wa.z, wa.w, wb.x, wb.y, wb.z, wb.w};

  float lmax = -INFINITY;
#pragma unroll
  for (int k = 0; k < 8; ++k) {
    float s = wh1 + v[k];
    s = s > 0.f ? s : ALPHA * s;
    s = ((m8 >> k) & 1u) ? s : NEGV;
    v[k] = s;
    lmax = fmaxf(lmax, s);
  }

  __shared__ float redm[4], reds[4];
#pragma unroll
  for (int off = 32; off > 0; off >>= 1) lmax = fmaxf(lmax, __shfl_xor(lmax, off));
  if (lane == 0) redm[wv] = lmax;
  __syncthreads();
  float m = fmaxf(fmaxf(redm[0], redm[1]), fmaxf(redm[2], redm[3]));

  float lsum = 0.f;
#pragma unroll
  for (int k = 0; k < 8; ++k) {
    float p = __expf(v[k] - m);
    v[k] = p;
    lsum += p;
  }
#pragma unroll
  for (int off = 32; off > 0; off >>= 1) lsum += __shfl_xor(lsum, off);
  if (lane == 0) reds[wv] = lsum;
  __syncthreads();
  float inv = 1.f / (reds[0] + reds[1] + reds[2] + reds[3]);

  short8v o;
#pragma unroll
  for (int k = 0; k < 8; ++k) o[k] = f2bf(v[k] * inv);
  *(short8v*)(att + (long)row * NN + t * 8) = o;
}

// ---------------------------------------------------------------------------
extern "C" void kernel_launch(void* const* d_in, const int* in_sizes, int n_in,
                              void* d_out, int out_size, void* d_ws,
                              size_t ws_size, hipStream_t stream) {
  const int* node_feats = (const int*)d_in[0];
  const int* adjs = (const int*)d_in[1];
  const float* embed_table = (const float*)d_in[2];
  const float* W_heads = (const float*)d_in[3];
  const float* a_heads = (const float*)d_in[4];
  const float* W_out = (const float*)d_in[5];
  const float* a_out = (const float*)d_in[6];
  float* out = (float*)d_out;

  // workspace layout (~215 MB)
  char* p = (char*)d_ws;
  short* Wt_o = (short*)p;  p += (size_t)HID * (NHEADS * HID) * 2;       // 4.7 MB
  short* Wh_t = (short*)p;  p += (size_t)BB * HID * NN * 2;              // 25 MB
  short* att2 = (short*)p;  p += (size_t)BB * NN * NN * 2;               // 67 MB
  short* hcat = (short*)p;  p += (size_t)MTOT * NHEADS * HID * 2;        // 100 MB
  unsigned long long* padj = (unsigned long long*)p;
  p += (size_t)BB * NN * NN / 8;                                         // 4.2 MB
  float* P16 = (float*)p;   p += (size_t)NHEADS * 16384 * 16 * 4;        // 4 MB
  // zero region (ZERO_B*256 floats): Wh1, Wh2, TW1, TW2, pad
  float* Wh1 = (float*)p;   p += (size_t)16384 * 4;
  float* Wh2 = (float*)p;   p += (size_t)16384 * 4;
  float* TW1 = (float*)p;   p += (size_t)64 * 4;
  float* TW2 = (float*)p;   p += (size_t)64 * 4;
  p += (size_t)(ZERO_B * 256 - 2 * 16384 - 128) * 4;  // pad (zeroed)
  float* TWp = (float*)p;   p += (size_t)16 * VOCAB * NHEADS * HID * 4;  // 2.9 MB
  float* TW = (float*)p;    p += (size_t)VOCAB * NHEADS * HID * 4;
  unsigned long long* nfm = (unsigned long long*)p;
  p += (size_t)BB * VOCAB * 32 * 8;                                      // 30 KB
  if ((size_t)(p - (char*)d_ws) > ws_size) return;

  // 0) mega-setup: vectorized adj pack + zeros + vocab masks + transpose + TW
  setup_kernel<<<PACK_B + ZERO_B + NFM_B + TRAN_B + TW_B, 256, 0, stream>>>(
      adjs, padj, Wh1, node_feats, nfm, W_out, Wt_o, embed_table, W_heads,
      TWp);

  // 1) layer 1: TW reduce + a-dots (fused), popcount-P16, expand
  tw_finish_kernel<<<12, 256, 0, stream>>>(TWp, TW, a_heads, TW1, TW2);
  p16_kernel<<<16384 / 4, 256, 0, stream>>>(
      node_feats, (const unsigned*)padj, (const unsigned*)nfm, TW1, TW2, P16);
  hcat_expand<<<dim3(24, 128), 256, 0, stream>>>(TW, P16, hcat);

  // 2) output GAT layer (full-rank): proj2 -> Wh_t + Wh1/Wh2 atomics
  mfma_gemm<0><<<dim3(HID / 256, MTOT / 256, 1), 512, 0, stream>>>(
      hcat, Wt_o, NHEADS * HID, NHEADS * HID, NHEADS * HID, 0, 0,
      nullptr, Wh_t, a_out, Wh1, Wh2);
  attn_softmax_kernel<<<MTOT, 256, 0, stream>>>(Wh1, Wh2, padj, att2, out, 24);
  mfma_gemm<3><<<dim3(HID / 256, NN / 256, BB), 512, 0, stream>>>(
      att2, Wh_t, NN, NN, NN, (long)NN * NN, (long)HID * NN,
      out, nullptr, nullptr, nullptr, nullptr);
}

// Round 11
// 439.119 us; speedup vs baseline: 1.1092x; 1.0096x over previous
//
#include <hip/hip_runtime.h>
#include <math.h>

#define BB 8
#define NN 2048
#define HID 768
#define NHEADS 4
#define VOCAB 15
#define ALPHA 0.2f
#define NEGV -9e15f
#define MTOT (BB * NN)  // 16384

using short4v = __attribute__((ext_vector_type(4))) short;
using short8v = __attribute__((ext_vector_type(8))) short;
using f32x4 = __attribute__((ext_vector_type(4))) float;

__device__ __forceinline__ short f2bf(float f) {
  union { float f; unsigned u; } x;
  x.f = f;
  unsigned r = x.u + 0x7fffu + ((x.u >> 16) & 1u);
  return (short)(r >> 16);
}

__device__ __forceinline__ void cp16(const void* g, void* l) {
  __builtin_amdgcn_global_load_lds(
      (const __attribute__((address_space(1))) unsigned int*)g,
      (__attribute__((address_space(3))) unsigned int*)l, 16, 0, 0);
}

// pack 8 bytes' low nibbles (LE order) into 32 bits
__device__ __forceinline__ unsigned long long nibcompress(unsigned long long x) {
  x = (x | (x >> 4)) & 0x00FF00FF00FF00FFull;
  x = (x | (x >> 8)) & 0x0000FFFF0000FFFFull;
  x = (x | (x >> 16)) & 0x00000000FFFFFFFFull;
  return x;
}

#define MEMFENCE asm volatile("" ::: "memory")
#define SBAR()                         \
  do {                                 \
    MEMFENCE;                          \
    __builtin_amdgcn_s_barrier();      \
    MEMFENCE;                          \
  } while (0)

// ---------------------------------------------------------------------------
// Mega-setup: [0,PACK_B) adjacency bit-pack, int4-vectorized (1024/block);
// [+ZERO_B) zero {Wh1,Wh2,TW1,TW2,pad}; [+NFM_B) per-batch vocab bitmasks;
// [+TRAN_B) W_out transpose; [+TW_B) TW partials (per-ky disjoint slots).
// ---------------------------------------------------------------------------
#define PACK_B 32768
#define ZERO_B 308
#define NFM_B 64
#define TRAN_B 2304  // 96 x 24 tiles of 32x32
#define TW_B 192     // 12 col-chunks x 16 k-chunks
__global__ __launch_bounds__(256) void setup_kernel(
    const int* __restrict__ adj, unsigned long long* __restrict__ packed,
    float* __restrict__ zbase, const int* __restrict__ nf,
    unsigned long long* __restrict__ nfm, const float* __restrict__ W_out,
    short* __restrict__ Wt_o, const float* __restrict__ table,
    const float* __restrict__ W_heads, float* __restrict__ TWp) {
  const int bid = blockIdx.x;
  const int tid = threadIdx.x;
  if (bid < PACK_B) {
    __shared__ unsigned long long nibq[32];
    long base = (long)bid * 1024;
    int4 a = *(const int4*)(adj + base + tid * 4);
    unsigned nib = (a.x > 0 ? 1u : 0u) | (a.y > 0 ? 2u : 0u) |
                   (a.z > 0 ? 4u : 0u) | (a.w > 0 ? 8u : 0u);
    ((unsigned char*)nibq)[tid] = (unsigned char)nib;
    __syncthreads();
    if (tid < 16) {
      unsigned long long lo = nibcompress(nibq[2 * tid]);
      unsigned long long hi = nibcompress(nibq[2 * tid + 1]);
      packed[(base >> 6) + tid] = lo | (hi << 32);
    }
  } else if (bid < PACK_B + ZERO_B) {
    zbase[(bid - PACK_B) * 256 + tid] = 0.f;
  } else if (bid < PACK_B + ZERO_B + NFM_B) {
    int r = bid - PACK_B - ZERO_B;  // 0..63
    int b = r >> 3, c = r & 7;
    int w = tid >> 6;
    int j = c * 256 + tid;
    int nfv = nf[b * NN + j];
#pragma unroll
    for (int v = 0; v < VOCAB; ++v) {
      unsigned long long m = __ballot(nfv == v);
      if ((tid & 63) == 0) nfm[((long)b * VOCAB + v) * 32 + c * 4 + w] = m;
    }
  } else if (bid < PACK_B + ZERO_B + NFM_B + TRAN_B) {
    // W_out transpose (3072x768 -> bf16 768x3072)
    __shared__ float t[32][33];
    int r2 = bid - PACK_B - ZERO_B - NFM_B;
    const int K = NHEADS * HID, N = HID;
    int k0 = (r2 % 96) * 32, n0 = (r2 / 96) * 32;
    int tx = tid & 31, ty = tid >> 5;
#pragma unroll
    for (int i = 0; i < 32; i += 8)
      t[ty + i][tx] = W_out[(long)(k0 + ty + i) * N + n0 + tx];
    __syncthreads();
#pragma unroll
    for (int i = 0; i < 32; i += 8)
      Wt_o[(long)(n0 + ty + i) * K + k0 + tx] = f2bf(t[tx][ty + i]);
  } else {
    // TW partial: col-chunk cx (256 cols), k-chunk ky (48 k) -> disjoint slot
    __shared__ float tbl[VOCAB][48];
    int r3 = bid - PACK_B - ZERO_B - NFM_B - TRAN_B;  // 0..191
    const int cx = r3 % 12, ky = r3 / 12;
    const int c = cx * 256 + tid;
    const int h = (cx * 256) / HID;
    const int n = c - h * HID;
    const int k0 = ky * 48;
    for (int idx = tid; idx < VOCAB * 48; idx += 256)
      tbl[idx / 48][idx % 48] = table[(idx / 48) * HID + k0 + idx % 48];
    __syncthreads();
    float acc[VOCAB];
#pragma unroll
    for (int v = 0; v < VOCAB; ++v) acc[v] = 0.f;
    const float* wp = W_heads + (long)h * HID * HID + (long)k0 * HID + n;
#pragma unroll 8
    for (int kk = 0; kk < 48; ++kk) {
      float w = wp[(long)kk * HID];
#pragma unroll
      for (int v = 0; v < VOCAB; ++v) acc[v] = fmaf(tbl[v][kk], w, acc[v]);
    }
#pragma unroll
    for (int v = 0; v < VOCAB; ++v)
      TWp[((long)ky * VOCAB + v) * (NHEADS * HID) + c] = acc[v];
  }
}

// ---------------------------------------------------------------------------
// Fused: reduce 16 TW partials -> TW, and accumulate a-dot partials into
// TW1/TW2 (zeroed by setup) via per-block reduce + atomicAdd. grid 12.
// ---------------------------------------------------------------------------
__global__ __launch_bounds__(256) void tw_finish_kernel(
    const float* __restrict__ TWp, float* __restrict__ TW,
    const float* __restrict__ a_heads, float* __restrict__ TW1,
    float* __restrict__ TW2) {
  const int tid = threadIdx.x;
  const int c = blockIdx.x * 256 + tid;  // 0..3071
  const int h = (blockIdx.x * 256) / HID;  // uniform per block
  const int n = c - h * HID;
  const float a1 = a_heads[h * 2 * HID + n];
  const float a2 = a_heads[h * 2 * HID + HID + n];
  const int lane = tid & 63;
  const int wv = tid >> 6;
  __shared__ float red[4][2 * VOCAB];

  float s1[VOCAB], s2[VOCAB];
#pragma unroll
  for (int v = 0; v < VOCAB; ++v) {
    float s = 0.f;
#pragma unroll
    for (int ky = 0; ky < 16; ++ky)
      s += TWp[((long)ky * VOCAB + v) * (NHEADS * HID) + c];
    TW[v * (NHEADS * HID) + c] = s;
    s1[v] = s * a1;
    s2[v] = s * a2;
  }
#pragma unroll
  for (int off = 1; off < 64; off <<= 1)
#pragma unroll
    for (int v = 0; v < VOCAB; ++v) {
      s1[v] += __shfl_xor(s1[v], off);
      s2[v] += __shfl_xor(s2[v], off);
    }
  if (lane == 0) {
#pragma unroll
    for (int v = 0; v < VOCAB; ++v) {
      red[wv][v] = s1[v];
      red[wv][VOCAB + v] = s2[v];
    }
  }
  __syncthreads();
  if (tid < 2 * VOCAB) {
    float s = red[0][tid] + red[1][tid] + red[2][tid] + red[3][tid];
    float* dst = (tid < VOCAB) ? (TW1 + h * VOCAB + tid)
                               : (TW2 + h * VOCAB + tid - VOCAB);
    atomicAdd(dst, s);
  }
}

// ---------------------------------------------------------------------------
// P16 via popcount: one wave per row; 15-value softmax for all 4 heads.
// ---------------------------------------------------------------------------
__global__ __launch_bounds__(256) void p16_kernel(
    const int* __restrict__ nf, const unsigned* __restrict__ padj32,
    const unsigned* __restrict__ nfm32, const float* __restrict__ TW1,
    const float* __restrict__ TW2, float* __restrict__ P16) {
  const int t = threadIdx.x;
  const int wv = t >> 6;
  const int lane = t & 63;
  const int rowm = blockIdx.x * 4 + wv;
  const int b = rowm >> 11;
  __shared__ float cnts[4][16];

  unsigned a = padj32[(long)rowm * 64 + lane];
  const unsigned* nb = nfm32 + (long)b * VOCAB * 64 + lane;
  int cnt[VOCAB];
#pragma unroll
  for (int v = 0; v < VOCAB; ++v) cnt[v] = __popc(a & nb[v * 64]);
#pragma unroll
  for (int off = 1; off < 64; off <<= 1)
#pragma unroll
    for (int v = 0; v < VOCAB; ++v) cnt[v] += __shfl_xor(cnt[v], off);
  int cntsum = 0;
#pragma unroll
  for (int v = 0; v < VOCAB; ++v) cntsum += cnt[v];
  const bool use_full = (cntsum == 0);  // wave-uniform
  if (use_full) {
#pragma unroll
    for (int v = 0; v < VOCAB; ++v) cnt[v] = __popc(nb[v * 64]);
#pragma unroll
    for (int off = 1; off < 64; off <<= 1)
#pragma unroll
      for (int v = 0; v < VOCAB; ++v) cnt[v] += __shfl_xor(cnt[v], off);
  }
  if (lane < 16) cnts[wv][lane] = (lane < VOCAB) ? (float)cnt[lane] : 0.f;
  __syncthreads();

  const int h = lane >> 4;
  const int v = lane & 15;
  const int nfi = nf[b * NN + (rowm & 2047)];
  float cvf = cnts[wv][v];
  bool valid = (v < VOCAB) && (cvf > 0.f);
  float logit = 0.f;
  if (!use_full) {
    float s = TW1[h * VOCAB + nfi] + ((v < VOCAB) ? TW2[h * VOCAB + v] : 0.f);
    logit = s > 0.f ? s : ALPHA * s;
  }
  float mv = valid ? logit : -INFINITY;
#pragma unroll
  for (int off = 1; off < 16; off <<= 1) mv = fmaxf(mv, __shfl_xor(mv, off));
  float pv = valid ? cvf * __expf(logit - mv) : 0.f;
  float sum = pv;
#pragma unroll
  for (int off = 1; off < 16; off <<= 1) sum += __shfl_xor(sum, off);
  if (v < VOCAB) P16[((long)h * 16384 + rowm) * 16 + v] = pv / sum;
}

// ---------------------------------------------------------------------------
// hcat[r][h*HID+colh] = ELU( sum_v P16[h][r][v] * TW[v][h*HID+colh] ) -> bf16
// ---------------------------------------------------------------------------
__global__ __launch_bounds__(256) void hcat_expand(
    const float* __restrict__ TW, const float* __restrict__ P16,
    short* __restrict__ hcat) {
  __shared__ float twl[VOCAB * 128];
  __shared__ float pl[128 * 16];
  const int c0 = blockIdx.x * 128;
  const int r0 = blockIdx.y * 128;
  const int h = c0 / HID;
  const int t = threadIdx.x;
  for (int idx = t; idx < VOCAB * 128; idx += 256)
    twl[idx] = TW[(idx / 128) * (NHEADS * HID) + c0 + (idx & 127)];
  for (int idx = t; idx < 128 * 16; idx += 256)
    pl[idx] = P16[((long)h * 16384 + r0 + (idx >> 4)) * 16 + (idx & 15)];
  __syncthreads();
  const int clb = (t & 31) * 4;
  const int rlb = (t >> 5) * 16;
#pragma unroll 4
  for (int rr = 0; rr < 16; ++rr) {
    int rl = rlb + rr;
    short4v o;
#pragma unroll
    for (int cc = 0; cc < 4; ++cc) {
      float s = 0.f;
#pragma unroll
      for (int vv = 0; vv < VOCAB; ++vv)
        s = fmaf(pl[rl * 16 + vv], twl[vv * 128 + clb + cc], s);
      s = s > 0.f ? s : (__expf(s) - 1.f);
      o[cc] = f2bf(s);
    }
    *(short4v*)(hcat + (long)(r0 + rl) * (NHEADS * HID) + c0 + clb) = o;
  }
}

// ---------------------------------------------------------------------------
// bf16 MFMA GEMM, 256x256 tile, BK=64, 512 threads (8 waves, 2Mx4N).
// 4 phases/K-tile: {stage-issue || ds_read quadrant || bar; lgkm0; 16 MFMA}.
// Counted vmcnt(4) once per K-tile (never 0 mid-loop); LDS K-chunk XOR
// swizzle slot = c ^ (row&7) via pre-swizzled global source (linear
// global_load_lds dest) + swizzled ds_read. Double-buffered 128 KiB LDS.
//   Buffer ledger (tile t in buf[t&1]):
//     t+1's B issued at t.q0 (buf p^1 dead since (t-1).q2-lgkm + barrier)
//     t+2's A issued at t.q3 (buf p   dead since   t  .q2-lgkm + barrier)
//     vmcnt(4) at t.q3 drains t+1's B (4/thread), keeps t+2's A in flight.
// MODE 0: a-dot atomics + transposed bf16 Ct [bb][colh][row] (layer 2).
// MODE 3: fused ELU + mean-pool: atomicAdd Cf[z*HID + col].
// ---------------------------------------------------------------------------
template <int MODE>
__global__ __launch_bounds__(512, 2) void mfma_gemm(
    const short* __restrict__ A, const short* __restrict__ B,
    int K, int lda, int ldb, long sA, long sB,
    float* __restrict__ Cf, short* __restrict__ Ct,
    const float* __restrict__ a_vec, float* __restrict__ Wh1g,
    float* __restrict__ Wh2g) {
  __shared__ short lds[2][2][16384];  // [buf][A/B][256 rows * 64 k] = 128 KiB

  const int gx = gridDim.x, gy = gridDim.y;
  int linb = blockIdx.x + gx * (blockIdx.y + gy * blockIdx.z);
  const int per = (gx * gy * gridDim.z) >> 3;
  int work = (linb & 7) * per + (linb >> 3);
  const int bx = work % gx;
  int tmpw = work / gx;
  const int by = tmpw % gy;
  const int z = tmpw / gy;

  A += (long)z * sA;
  B += (long)z * sB;

  const int tid = threadIdx.x;
  const int m0 = by * 256;
  const int n0 = bx * 256;
  const int lane = tid & 63;
  const int wid = tid >> 6;
  const int wr = wid >> 2;  // 0..1  (M half)
  const int wc = wid & 3;   // 0..3  (N quarter)
  const int l15 = lane & 15;
  const int quad = lane >> 4;
  const int NT = K >> 6;

  // swizzled ds_read chunk offset (shorts); kh=1 is ^32
  const int cbase = (quad ^ (l15 & 7)) << 3;

  auto stageA = [&](int kt, int h) {
    const short* src = A + (long)(m0 + h * 128) * lda + kt * 64;
    short* dst = &lds[kt & 1][0][h * 8192];
#pragma unroll
    for (int it = 0; it < 2; ++it) {
      int lin2 = it * 256 + tid;
      int r = it * 64 + (tid >> 3);
      int s = tid & 7;
      (void)lin2;
      cp16(src + (long)r * lda + ((s ^ (r & 7)) << 3),
           dst + (it * 512 + tid) * 8);
    }
  };
  auto stageB = [&](int kt, int h) {
    const short* src = B + (long)(n0 + h * 128) * ldb + kt * 64;
    short* dst = &lds[kt & 1][1][h * 8192];
#pragma unroll
    for (int it = 0; it < 2; ++it) {
      int r = it * 64 + (tid >> 3);
      int s = tid & 7;
      cp16(src + (long)r * ldb + ((s ^ (r & 7)) << 3),
           dst + (it * 512 + tid) * 8);
    }
  };

  f32x4 acc[8][4];
#pragma unroll
  for (int i = 0; i < 8; ++i)
#pragma unroll
    for (int j = 0; j < 4; ++j) acc[i][j] = (f32x4){0.f, 0.f, 0.f, 0.f};

  // prologue: tile0 fully, tile1's A (kept in flight across the wait)
  stageA(0, 0); stageA(0, 1);
  stageB(0, 0); stageB(0, 1);
  stageA(1, 0); stageA(1, 1);
  asm volatile("s_waitcnt vmcnt(4)" ::: "memory");
  SBAR();

#pragma unroll 1
  for (int t = 0; t < NT; ++t) {
    const int p = t & 1;
    const short* Ab = &lds[p][0][0];
    const short* Bb = &lds[p][1][0];
    short8v a[4][2], b0[2][2], b1[2][2];

    // ---- q0: issue t+1's B; read A(qm=0) + B(qn=0); MFMA Q00 ----
    if (t + 1 < NT) { stageB(t + 1, 0); stageB(t + 1, 1); }
#pragma unroll
    for (int ii = 0; ii < 4; ++ii) {
      int ro = (wr * 128 + ii * 16 + l15) * 64;
      a[ii][0] = *(const short8v*)(Ab + ro + cbase);
      a[ii][1] = *(const short8v*)(Ab + ro + (cbase ^ 32));
    }
#pragma unroll
    for (int jj = 0; jj < 2; ++jj) {
      int ro = (wc * 64 + jj * 16 + l15) * 64;
      b0[jj][0] = *(const short8v*)(Bb + ro + cbase);
      b0[jj][1] = *(const short8v*)(Bb + ro + (cbase ^ 32));
    }
    SBAR();
    asm volatile("s_waitcnt lgkmcnt(0)" ::: "memory");
    __builtin_amdgcn_sched_barrier(0);
    __builtin_amdgcn_s_setprio(1);
#pragma unroll
    for (int ii = 0; ii < 4; ++ii)
#pragma unroll
      for (int jj = 0; jj < 2; ++jj) {
        acc[ii][jj] = __builtin_amdgcn_mfma_f32_16x16x32_bf16(a[ii][0], b0[jj][0],
                                                              acc[ii][jj], 0, 0, 0);
        acc[ii][jj] = __builtin_amdgcn_mfma_f32_16x16x32_bf16(a[ii][1], b0[jj][1],
                                                              acc[ii][jj], 0, 0, 0);
      }
    __builtin_amdgcn_sched_barrier(0);
    __builtin_amdgcn_s_setprio(0);
    SBAR();

    // ---- q1: read B(qn=1); MFMA Q01 ----
#pragma unroll
    for (int jj = 0; jj < 2; ++jj) {
      int ro = (wc * 64 + 32 + jj * 16 + l15) * 64;
      b1[jj][0] = *(const short8v*)(Bb + ro + cbase);
      b1[jj][1] = *(const short8v*)(Bb + ro + (cbase ^ 32));
    }
    SBAR();
    asm volatile("s_waitcnt lgkmcnt(0)" ::: "memory");
    __builtin_amdgcn_sched_barrier(0);
    __builtin_amdgcn_s_setprio(1);
#pragma unroll
    for (int ii = 0; ii < 4; ++ii)
#pragma unroll
      for (int jj = 0; jj < 2; ++jj) {
        acc[ii][2 + jj] = __builtin_amdgcn_mfma_f32_16x16x32_bf16(
            a[ii][0], b1[jj][0], acc[ii][2 + jj], 0, 0, 0);
        acc[ii][2 + jj] = __builtin_amdgcn_mfma_f32_16x16x32_bf16(
            a[ii][1], b1[jj][1], acc[ii][2 + jj], 0, 0, 0);
      }
    __builtin_amdgcn_sched_barrier(0);
    __builtin_amdgcn_s_setprio(0);
    SBAR();

    // ---- q2: read A(qm=1); MFMA Q11 ----
#pragma unroll
    for (int ii = 0; ii < 4; ++ii) {
      int ro = (wr * 128 + 64 + ii * 16 + l15) * 64;
      a[ii][0] = *(const short8v*)(Ab + ro + cbase);
      a[ii][1] = *(const short8v*)(Ab + ro + (cbase ^ 32));
    }
    SBAR();
    asm volatile("s_waitcnt lgkmcnt(0)" ::: "memory");
    __builtin_amdgcn_sched_barrier(0);
    __builtin_amdgcn_s_setprio(1);
#pragma unroll
    for (int ii = 0; ii < 4; ++ii)
#pragma unroll
      for (int jj = 0; jj < 2; ++jj) {
        acc[4 + ii][2 + jj] = __builtin_amdgcn_mfma_f32_16x16x32_bf16(
            a[ii][0], b1[jj][0], acc[4 + ii][2 + jj], 0, 0, 0);
        acc[4 + ii][2 + jj] = __builtin_amdgcn_mfma_f32_16x16x32_bf16(
            a[ii][1], b1[jj][1], acc[4 + ii][2 + jj], 0, 0, 0);
      }
    __builtin_amdgcn_sched_barrier(0);
    __builtin_amdgcn_s_setprio(0);
    SBAR();

    // ---- q3: issue t+2's A (buf p dead: q2 barrier passed); MFMA Q10;
    //          counted vmcnt keeps t+2's A in flight ----
    if (t + 2 < NT) { stageA(t + 2, 0); stageA(t + 2, 1); }
    __builtin_amdgcn_s_setprio(1);
#pragma unroll
    for (int ii = 0; ii < 4; ++ii)
#pragma unroll
      for (int jj = 0; jj < 2; ++jj) {
        acc[4 + ii][jj] = __builtin_amdgcn_mfma_f32_16x16x32_bf16(
            a[ii][0], b0[jj][0], acc[4 + ii][jj], 0, 0, 0);
        acc[4 + ii][jj] = __builtin_amdgcn_mfma_f32_16x16x32_bf16(
            a[ii][1], b0[jj][1], acc[4 + ii][jj], 0, 0, 0);
      }
    __builtin_amdgcn_sched_barrier(0);
    __builtin_amdgcn_s_setprio(0);
    if (t + 2 < NT) {
      asm volatile("s_waitcnt vmcnt(4)" ::: "memory");
    } else if (t + 1 < NT) {
      asm volatile("s_waitcnt vmcnt(0)" ::: "memory");
    }
    SBAR();
  }

  // ---- epilogues (C/D layout: col=l15, row=quad*4+reg per 16x16 frag) ----
  if constexpr (MODE == 3) {
#pragma unroll
    for (int nj = 0; nj < 4; ++nj) {
      int col = n0 + wc * 64 + nj * 16 + l15;
      float s = 0.f;
#pragma unroll
      for (int mi = 0; mi < 8; ++mi)
#pragma unroll
        for (int reg = 0; reg < 4; ++reg) {
          float v = acc[mi][nj][reg];
          s += v > 0.f ? v : (__expf(v) - 1.f);
        }
      s += __shfl_xor(s, 16);
      s += __shfl_xor(s, 32);
      if (quad == 0) atomicAdd(Cf + (long)z * HID + col, s * (1.0f / NN));
    }
  } else {  // MODE 0: a-dot atomics + direct transposed Ct store
    float a1v[4], a2v[4];
#pragma unroll
    for (int nj = 0; nj < 4; ++nj) {
      int colh = n0 + wc * 64 + nj * 16 + l15;  // < 768
      a1v[nj] = a_vec[colh];
      a2v[nj] = a_vec[HID + colh];
    }
#pragma unroll
    for (int mi = 0; mi < 8; ++mi) {
      int rb = m0 + wr * 128 + mi * 16 + quad * 4;
#pragma unroll
      for (int reg = 0; reg < 4; ++reg) {
        float s1 = 0.f, s2 = 0.f;
#pragma unroll
        for (int nj = 0; nj < 4; ++nj) {
          s1 = fmaf(acc[mi][nj][reg], a1v[nj], s1);
          s2 = fmaf(acc[mi][nj][reg], a2v[nj], s2);
        }
#pragma unroll
        for (int off = 1; off < 16; off <<= 1) {
          s1 += __shfl_xor(s1, off);
          s2 += __shfl_xor(s2, off);
        }
        if (l15 == 0) {
          atomicAdd(Wh1g + rb + reg, s1);
          atomicAdd(Wh2g + rb + reg, s2);
        }
      }
    }
    const int bb = m0 >> 11;
    const int ml0 = (m0 & 2047) + wr * 128;
#pragma unroll
    for (int mi = 0; mi < 8; ++mi) {
#pragma unroll
      for (int nj = 0; nj < 4; ++nj) {
        int colh = n0 + wc * 64 + nj * 16 + l15;
        short4v pk;
#pragma unroll
        for (int reg = 0; reg < 4; ++reg) pk[reg] = f2bf(acc[mi][nj][reg]);
        *(short4v*)(Ct + ((long)bb * HID + colh) * NN + ml0 + mi * 16 +
                    quad * 4) = pk;
      }
    }
  }
}

// ---------------------------------------------------------------------------
// Layer-2 row softmax (materializing, bf16 att). grid 16384. Blocks [0,zn)
// also zero zA (final output accumulator; write-disjoint from reads).
// ---------------------------------------------------------------------------
__global__ __launch_bounds__(256) void attn_softmax_kernel(
    const float* __restrict__ Wh1, const float* __restrict__ Wh2,
    const unsigned long long* __restrict__ packed, short* __restrict__ att,
    float* __restrict__ zA, int zn) {
  int row = blockIdx.x;
  if (row < zn) zA[row * 256 + threadIdx.x] = 0.f;
  int b = row >> 11;
  const unsigned char* bits = (const unsigned char*)(packed + (long)row * 32);
  const float* wh2b = Wh2 + b * NN;
  const int t = threadIdx.x;
  const int lane = t & 63;
  const int wv = t >> 6;

  unsigned m8 = bits[t];
  float wh1 = Wh1[row];
  float4 wa = ((const float4*)(wh2b + t * 8))[0];
  float4 wb = ((const float4*)(wh2b + t * 8))[1];
  float v[8] = {wa.x, wa.y, wa.z, wa.w, wb.x, wb.y, wb.z, wb.w};

  float lmax = -INFINITY;
#pragma unroll
  for (int k = 0; k < 8; ++k) {
    float s = wh1 + v[k];
    s = s > 0.f ? s : ALPHA * s;
    s = ((m8 >> k) & 1u) ? s : NEGV;
    v[k] = s;
    lmax = fmaxf(lmax, s);
  }

  __shared__ float redm[4], reds[4];
#pragma unroll
  for (int off = 32; off > 0; off >>= 1) lmax = fmaxf(lmax, __shfl_xor(lmax, off));
  if (lane == 0) redm[wv] = lmax;
  __syncthreads();
  float m = fmaxf(fmaxf(redm[0], redm[1]), fmaxf(redm[2], redm[3]));

  float lsum = 0.f;
#pragma unroll
  for (int k = 0; k < 8; ++k) {
    float p = __expf(v[k] - m);
    v[k] = p;
    lsum += p;
  }
#pragma unroll
  for (int off = 32; off > 0; off >>= 1) lsum += __shfl_xor(lsum, off);
  if (lane == 0) reds[wv] = lsum;
  __syncthreads();
  float inv = 1.f / (reds[0] + reds[1] + reds[2] + reds[3]);

  short8v o;
#pragma unroll
  for (int k = 0; k < 8; ++k) o[k] = f2bf(v[k] * inv);
  *(short8v*)(att + (long)row * NN + t * 8) = o;
}

// ---------------------------------------------------------------------------
extern "C" void kernel_launch(void* const* d_in, const int* in_sizes, int n_in,
                              void* d_out, int out_size, void* d_ws,
                              size_t ws_size, hipStream_t stream) {
  const int* node_feats = (const int*)d_in[0];
  const int* adjs = (const int*)d_in[1];
  const float* embed_table = (const float*)d_in[2];
  const float* W_heads = (const float*)d_in[3];
  const float* a_heads = (const float*)d_in[4];
  const float* W_out = (const float*)d_in[5];
  const float* a_out = (const float*)d_in[6];
  float* out = (float*)d_out;

  // workspace layout (~215 MB)
  char* p = (char*)d_ws;
  short* Wt_o = (short*)p;  p += (size_t)HID * (NHEADS * HID) * 2;       // 4.7 MB
  short* Wh_t = (short*)p;  p += (size_t)BB * HID * NN * 2;              // 25 MB
  short* att2 = (short*)p;  p += (size_t)BB * NN * NN * 2;               // 67 MB
  short* hcat = (short*)p;  p += (size_t)MTOT * NHEADS * HID * 2;        // 100 MB
  unsigned long long* padj = (unsigned long long*)p;
  p += (size_t)BB * NN * NN / 8;                                         // 4.2 MB
  float* P16 = (float*)p;   p += (size_t)NHEADS * 16384 * 16 * 4;        // 4 MB
  // zero region (ZERO_B*256 floats): Wh1, Wh2, TW1, TW2, pad
  float* Wh1 = (float*)p;   p += (size_t)16384 * 4;
  float* Wh2 = (float*)p;   p += (size_t)16384 * 4;
  float* TW1 = (float*)p;   p += (size_t)64 * 4;
  float* TW2 = (float*)p;   p += (size_t)64 * 4;
  p += (size_t)(ZERO_B * 256 - 2 * 16384 - 128) * 4;  // pad (zeroed)
  float* TWp = (float*)p;   p += (size_t)16 * VOCAB * NHEADS * HID * 4;  // 2.9 MB
  float* TW = (float*)p;    p += (size_t)VOCAB * NHEADS * HID * 4;
  unsigned long long* nfm = (unsigned long long*)p;
  p += (size_t)BB * VOCAB * 32 * 8;                                      // 30 KB
  if ((size_t)(p - (char*)d_ws) > ws_size) return;

  // 0) mega-setup: vectorized adj pack + zeros + vocab masks + transpose + TW
  setup_kernel<<<PACK_B + ZERO_B + NFM_B + TRAN_B + TW_B, 256, 0, stream>>>(
      adjs, padj, Wh1, node_feats, nfm, W_out, Wt_o, embed_table, W_heads,
      TWp);

  // 1) layer 1: TW reduce + a-dots (fused), popcount-P16, expand
  tw_finish_kernel<<<12, 256, 0, stream>>>(TWp, TW, a_heads, TW1, TW2);
  p16_kernel<<<16384 / 4, 256, 0, stream>>>(
      node_feats, (const unsigned*)padj, (const unsigned*)nfm, TW1, TW2, P16);
  hcat_expand<<<dim3(24, 128), 256, 0, stream>>>(TW, P16, hcat);

  // 2) output GAT layer (full-rank): proj2 -> Wh_t + Wh1/Wh2 atomics
  mfma_gemm<0><<<dim3(HID / 256, MTOT / 256, 1), 512, 0, stream>>>(
      hcat, Wt_o, NHEADS * HID, NHEADS * HID, NHEADS * HID, 0, 0,
      nullptr, Wh_t, a_out, Wh1, Wh2);
  attn_softmax_kernel<<<MTOT, 256, 0, stream>>>(Wh1, Wh2, padj, att2, out, 24);
  mfma_gemm<3><<<dim3(HID / 256, NN / 256, BB), 512, 0, stream>>>(
      att2, Wh_t, NN, NN, NN, (long)NN * NN, (long)HID * NN,
      out, nullptr, nullptr, nullptr, nullptr);
}